// Round 14
// baseline (1044.682 us; speedup 1.0000x reference)
//
#include <hip/hip_runtime.h>

#define NNODE 16384
#define NEDGE 32768
#define NG    256
#define TPGx  12
#define TTOT  (NG * TPGx)   // 3072
#define D     64

typedef _Float16 h8 __attribute__((ext_vector_type(8)));
typedef _Float16 h4 __attribute__((ext_vector_type(4)));
typedef float    f4 __attribute__((ext_vector_type(4)));

static __device__ __forceinline__ float sigm(float x) { return 1.f / (1.f + __expf(-x)); }
static __device__ __forceinline__ float tanh_f(float x) {
  float t = __expf(2.f * x);
  return (t - 1.f) / (t + 1.f);
}

static __device__ __forceinline__ f4 mfma16h(h8 a, h8 b, f4 c) {
  return __builtin_amdgcn_mfma_f32_16x16x32_f16(a, b, c, 0, 0, 0);
}

static __device__ __forceinline__ h8 splat16(_Float16 x) {
  h8 v = {x, x, x, x, x, x, x, x};
  return v;
}

// ---------------- workspace layout (byte offsets) ----------------
#define WS_H      0          // float [N*64]   4 MiB
#define WS_AGG    4194304    // float [N*64]   4 MiB
#define WS_W2     8388608    // fp16 [65 tiles * 4096]; tile i idx=((k>>3)*64+o)*8+(k&7)
#define WS_RT     8921088    // fp16 [64*64]  rt[o][i]
#define WS_WHH    8929280    // fp16 [192*64] natural [oo][i]
#define WS_WIH    8953856    // fp16 [192*64]
#define WS_SWIHT  8978432    // f32 [128][256] transposed
#define WS_SWHHT  9109504    // f32 [64][256]  transposed
#define WS_MWIHT  9175040    // f32 [128][256] transposed
#define WS_L1WT   9306112    // f32 [320][64]  transposed
#define WS_L2WF   9388032    // f32 [6*64]
#define WS_FB     9389568    // f32 [2246]
#define WS_DEG    9398784    // f32 [N]
#define WS_HX     9464320    // f32 [G*64]
#define WS_NEED   9529856
// fb sub-offsets (floats): lin0w 0, lin0b 192, e1w 256, e1b 640, convb 704,
// gbih 768, gbhh 960, s2sbih 1152, s2sbhh 1408, membih 1664, membhh 1920,
// l1b 2176, l2b 2240

// ---------------- setup1: pack params + zero agg/deg ----------------
struct Srcs { const void* p[23]; };

__device__ __constant__ const int kCum[24] = {
    0, 192, 256, 640, 704, 262848, 266944, 271040, 271104, 283392, 295680,
    295872, 296064, 328832, 345216, 345472, 345728, 378496, 378752, 379008,
    399488, 399552, 399936, 399942};

__global__ __launch_bounds__(256) void setup1_kernel(Srcs S, char* __restrict__ ws) {
  int idx = blockIdx.x * 256 + threadIdx.x;
  if (idx < 399942) {
    int r = 0, base = 0;
#pragma unroll
    for (int k = 0; k < 23; k++)
      if (idx >= kCum[k]) { r = k; base = kCum[k]; }
    int li = idx - base;
    float v = ((const float*)S.p[r])[li];

    float*    fb    = (float*)(ws + WS_FB);
    _Float16* w2    = (_Float16*)(ws + WS_W2);
    _Float16* rtH   = (_Float16*)(ws + WS_RT);
    _Float16* whhH  = (_Float16*)(ws + WS_WHH);
    _Float16* wihH  = (_Float16*)(ws + WS_WIH);
    float*    swihT = (float*)(ws + WS_SWIHT);
    float*    swhhT = (float*)(ws + WS_SWHHT);
    float*    mwihT = (float*)(ws + WS_MWIHT);
    float*    l1wT  = (float*)(ws + WS_L1WT);
    float*    l2w   = (float*)(ws + WS_L2WF);

    switch (r) {
      case 0: fb[li] = v; break;          // lin0_w
      case 1: fb[192 + li] = v; break;    // lin0_b
      case 2: fb[256 + li] = v; break;    // e1_w
      case 3: fb[640 + li] = v; break;    // e1_b
      case 4: {                           // e2_w flat (i*64+o)*64+k -> tile i
        int i = li >> 12, o = (li >> 6) & 63, k = li & 63;
        w2[i * 4096 + (((k >> 3) * 64 + o) << 3) + (k & 7)] = (_Float16)v;
      } break;
      case 5: {                           // e2_b flat k*64+o -> tile 64
        int k = li >> 6, o = li & 63;
        w2[64 * 4096 + (((k >> 3) * 64 + o) << 3) + (k & 7)] = (_Float16)v;
      } break;
      case 6: {                           // root_w [i][o] -> rt[o*64+i]
        int i = li >> 6, o = li & 63;
        rtH[o * 64 + i] = (_Float16)v;
      } break;
      case 7: fb[704 + li] = v; break;    // conv_b
      case 8: wihH[li] = (_Float16)v; break;   // gru_wih [oo][i]
      case 9: whhH[li] = (_Float16)v; break;   // gru_whh [oo][i]
      case 10: fb[768 + li] = v; break;   // gru_bih
      case 11: fb[960 + li] = v; break;   // gru_bhh
      case 12: swihT[(li & 127) * 256 + (li >> 7)] = v; break;  // s2s_wih
      case 13: swhhT[(li & 63) * 256 + (li >> 6)] = v; break;   // s2s_whh
      case 14: fb[1152 + li] = v; break;  // s2s_bih
      case 15: fb[1408 + li] = v; break;  // s2s_bhh
      case 16: mwihT[(li & 127) * 256 + (li >> 7)] = v; break;  // mem_wih
      case 17: fb[1664 + li] = v; break;  // mem_bih
      case 18: fb[1920 + li] = v; break;  // mem_bhh
      case 19: l1wT[(li % 320) * 64 + (li / 320)] = v; break;   // lin1_w
      case 20: fb[2176 + li] = v; break;  // lin1_b
      case 21: l2w[li] = v; break;
      case 22: fb[2240 + li] = v; break;  // lin2_b
    }
    return;
  }
  idx -= 399942;
  float4 z4 = {0.f, 0.f, 0.f, 0.f};
  if (idx < 262144) { ((float4*)(ws + WS_AGG))[idx] = z4; return; }
  idx -= 262144;
  if (idx < 4096) ((float4*)(ws + WS_DEG))[idx] = z4;
}
#define SETUP1_N (399942 + 262144 + 4096)

// ---------------- setup2: node init (reads fb) + degree count ----------------
__global__ __launch_bounds__(256) void setup2_kernel(
    const float* __restrict__ x, const int* __restrict__ edge_index,
    char* __restrict__ ws) {
  int idx = blockIdx.x * 256 + threadIdx.x;
  if (idx < 262144) {   // h init, float4 per thread
    const float* fb = (const float*)(ws + WS_FB);
    float* h = (float*)(ws + WS_H);
    int n = idx >> 4, oq = idx & 15;
    float x0 = x[n * 3], x1 = x[n * 3 + 1], x2 = x[n * 3 + 2];
    float4 out;
#pragma unroll
    for (int c = 0; c < 4; c++) {
      int o = oq * 4 + c;
      float acc = fb[192 + o] + x0 * fb[o * 3] + x1 * fb[o * 3 + 1] + x2 * fb[o * 3 + 2];
      ((float*)&out)[c] = fmaxf(acc, 0.f);
    }
    *(float4*)&h[n * 64 + oq * 4] = out;
    return;
  }
  idx -= 262144;
  if (idx < NEDGE) {
    float* deg = (float*)(ws + WS_DEG);
    atomicAdd(&deg[edge_index[NEDGE + idx]], 1.0f);
  }
}
#define SETUP2_N (262144 + NEDGE)

// ---------------- message GEMM, fp16; K-split, 8 waves/block, 64 edges/block ------
// waves 0-3: tiles 0..31 for cols w*16..; waves 4-7: tiles 32..64 (+bias tail) for
// the same output tiles; upper waves deposit fp32 partials in LDS; lower waves sum
// and atomicAdd. Traffic identical to the 4-wave version; waves/CU doubles to 16.
__global__ __launch_bounds__(512, 4) void msg_kernel(
    const float* __restrict__ h, const float* __restrict__ ea,
    const float* __restrict__ fb, const _Float16* __restrict__ w2,
    const int* __restrict__ edge_index, float* __restrict__ agg) {
  __shared__ _Float16 sOut[64][72];      // 9 KB
  __shared__ float part[4][64][17];      // 17.4 KB upper-wave partials (padded)
  const int tid = threadIdx.x;
  const int wave = tid >> 6, lane = tid & 63;
  const int m15 = lane & 15, quad = lane >> 4;
  const int w4 = wave & 3;        // column group (nt)
  const int half = wave >> 2;     // K half: 0 -> tiles 0..31, 1 -> tiles 32..64
  const int eb = blockIdx.x * 64;
  {  // stage out[src] as fp16 for 64 edges (8 threads per row)
    int r = tid >> 3, c0 = (tid & 7) * 8;
    int srcn = edge_index[eb + r];
#pragma unroll
    for (int c = c0; c < c0 + 8; c += 4) {
      float4 v = *(const float4*)&h[srcn * D + c];
      sOut[r][c]     = (_Float16)v.x;
      sOut[r][c + 1] = (_Float16)v.y;
      sOut[r][c + 2] = (_Float16)v.z;
      sOut[r][c + 3] = (_Float16)v.w;
    }
  }
  // edge hidden (fp32 compute, fp16 store) for 4 edges/lane: e = eb + r*16 + m15
  h8 hid0[4], hid1[4];
#pragma unroll
  for (int r = 0; r < 4; r++) {
    int e = eb + r * 16 + m15;
    float eav[6];
#pragma unroll
    for (int j = 0; j < 6; j++) eav[j] = ea[e * 6 + j];
#pragma unroll
    for (int j = 0; j < 8; j++) {
      int k0 = quad * 8 + j, k1 = 32 + quad * 8 + j;
      float a0 = fb[640 + k0], a1 = fb[640 + k1];
#pragma unroll
      for (int jj = 0; jj < 6; jj++) {
        a0 += eav[jj] * fb[256 + k0 * 6 + jj];
        a1 += eav[jj] * fb[256 + k1 * 6 + jj];
      }
      hid0[r][j] = (_Float16)fmaxf(a0, 0.f);
      hid1[r][j] = (_Float16)fmaxf(a1, 0.f);
    }
  }
  __syncthreads();
  // per-lane B fragment pointers (L2-resident, coalesced dwordx4 per lane)
  const _Float16* bp0 = w2 + (quad * 64 + w4 * 16 + m15) * 8;        // kc = quad
  const _Float16* bp1 = w2 + ((4 + quad) * 64 + w4 * 16 + m15) * 8;  // kc = 4+quad
  const int tbase = half * 32;
  f4 zz = {0.f, 0.f, 0.f, 0.f};
  f4 acc[4];
#pragma unroll
  for (int r = 0; r < 4; r++) acc[r] = zz;
  h8 c0v[4], c1v[4];
#pragma unroll
  for (int t = 0; t < 4; t++) {
    c0v[t] = *(const h8*)(bp0 + (tbase + t) * 4096);
    c1v[t] = *(const h8*)(bp1 + (tbase + t) * 4096);
  }
#pragma unroll
  for (int p = 0; p < 8; p++) {
    h8 n0[4], n1[4];
    if (p < 7) {
#pragma unroll
      for (int t = 0; t < 4; t++) {
        int i = tbase + (p + 1) * 4 + t;
        n0[t] = *(const h8*)(bp0 + i * 4096);
        n1[t] = *(const h8*)(bp1 + i * 4096);
      }
    }
#pragma unroll
    for (int r = 0; r < 4; r++) {
      h4 os4 = *(const h4*)&sOut[r * 16 + m15][tbase + p * 4];
#pragma unroll
      for (int t = 0; t < 4; t++) {
        h8 os = splat16(os4[t]);
        acc[r] = mfma16h(hid0[r] * os, c0v[t], acc[r]);
        acc[r] = mfma16h(hid1[r] * os, c1v[t], acc[r]);
      }
    }
    if (p < 7) {
#pragma unroll
      for (int t = 0; t < 4; t++) { c0v[t] = n0[t]; c1v[t] = n1[t]; }
    }
  }
  if (half == 1) {
    {  // bias tail (tile 64): z = out_src
      h8 b0 = *(const h8*)(bp0 + 64 * 4096);
      h8 b1 = *(const h8*)(bp1 + 64 * 4096);
#pragma unroll
      for (int r = 0; r < 4; r++) {
        h8 a0 = *(const h8*)&sOut[r * 16 + m15][quad * 8];
        h8 a1 = *(const h8*)&sOut[r * 16 + m15][32 + quad * 8];
        acc[r] = mfma16h(a0, b0, acc[r]);
        acc[r] = mfma16h(a1, b1, acc[r]);
      }
    }
#pragma unroll
    for (int r = 0; r < 4; r++)
#pragma unroll
      for (int reg = 0; reg < 4; reg++)
        part[w4][r * 16 + quad * 4 + reg][m15] = acc[r][reg];
  }
  __syncthreads();
  if (half == 0) {
#pragma unroll
    for (int r = 0; r < 4; r++) {
#pragma unroll
      for (int reg = 0; reg < 4; reg++) {
        int el = r * 16 + quad * 4 + reg;
        float v = acc[r][reg] + part[w4][el][m15];
        int dn = edge_index[NEDGE + eb + el];
        atomicAdd(agg + dn * D + w4 * 16 + m15, v);
      }
    }
  }
}

// ---------------- node update: 1 wave = 16 nodes; single-wave block ----
__global__ __launch_bounds__(64) void update_kernel(
    float* __restrict__ h, float* __restrict__ agg, const float* __restrict__ deg,
    const _Float16* __restrict__ rtH, const _Float16* __restrict__ whhH,
    const _Float16* __restrict__ wihH, const float* __restrict__ fb) {
  __shared__ float bufH[16][68];
  __shared__ float bufM[16][68];
  const int lane = threadIdx.x;
  const int m15 = lane & 15, quad = lane >> 4;
  const int nb = blockIdx.x * 16;
  {
    int r = lane >> 2, c0 = (lane & 3) * 16;
#pragma unroll
    for (int c = c0; c < c0 + 16; c += 4)
      *(float4*)&bufH[r][c] = *(const float4*)&h[(nb + r) * D + c];
  }
  __syncthreads();  // single wave: waitcnt only
  h8 a0, a1;
#pragma unroll
  for (int j = 0; j < 8; j++) {
    a0[j] = (_Float16)bufH[m15][quad * 8 + j];
    a1[j] = (_Float16)bufH[m15][32 + quad * 8 + j];
  }
  f4 zz = {0.f, 0.f, 0.f, 0.f};
  f4 acc[16];
#pragma unroll
  for (int nt = 0; nt < 16; nt++) acc[nt] = zz;
#pragma unroll
  for (int nt = 0; nt < 16; nt++) {
    int nn = nt * 16 + m15;
    const _Float16* bp = (nt < 4) ? (rtH + nn * D) : (whhH + (nn - 64) * D);
    h8 bh0 = *(const h8*)(bp + quad * 8);
    h8 bh1 = *(const h8*)(bp + 32 + quad * 8);
    f4 a = acc[nt];
    a = mfma16h(a0, bh0, a);
    a = mfma16h(a1, bh1, a);
    acc[nt] = a;
  }
  // m = relu(root + agg/deg + conv_b), fp32, into bufM; zero agg behind us
#pragma unroll
  for (int nt = 0; nt < 4; nt++) {
#pragma unroll
    for (int reg = 0; reg < 4; reg++) {
      int nloc = quad * 4 + reg;
      int o = nt * 16 + m15;
      float dg = fmaxf(deg[nb + nloc], 1.f);
      int aidx = (nb + nloc) * D + o;
      float v = acc[nt][reg] + agg[aidx] / dg + fb[704 + o];
      agg[aidx] = 0.f;
      bufM[nloc][o] = fmaxf(v, 0.f);
    }
  }
  __syncthreads();
  h8 m0, m1;
#pragma unroll
  for (int j = 0; j < 8; j++) {
    m0[j] = (_Float16)bufM[m15][quad * 8 + j];
    m1[j] = (_Float16)bufM[m15][32 + quad * 8 + j];
  }
  f4 g2[12];
#pragma unroll
  for (int nt = 0; nt < 12; nt++) g2[nt] = zz;
#pragma unroll
  for (int nt = 0; nt < 12; nt++) {
    int nn = nt * 16 + m15;
    const _Float16* bp = wihH + nn * D;
    h8 bh0 = *(const h8*)(bp + quad * 8);
    h8 bh1 = *(const h8*)(bp + 32 + quad * 8);
    f4 a = g2[nt];
    a = mfma16h(m0, bh0, a);
    a = mfma16h(m1, bh1, a);
    g2[nt] = a;
  }
#pragma unroll
  for (int nt = 0; nt < 4; nt++) {
#pragma unroll
    for (int reg = 0; reg < 4; reg++) {
      int nloc = quad * 4 + reg;
      int o = nt * 16 + m15;
      int gidx = (nb + nloc) * D + o;
      float gir = g2[nt][reg]      + fb[768 + o];
      float giz = g2[nt + 4][reg]  + fb[768 + 64 + o];
      float gin = g2[nt + 8][reg]  + fb[768 + 128 + o];
      float ghr = acc[nt + 4][reg]  + fb[960 + o];
      float ghz = acc[nt + 8][reg]  + fb[960 + 64 + o];
      float ghn = acc[nt + 12][reg] + fb[960 + 128 + o];
      float rr = sigm(gir + ghr);
      float zg = sigm(giz + ghz);
      float nnv = tanh_f(gin + rr * ghn);
      float hv = h[gidx];
      h[gidx] = (1.f - zg) * nnv + zg * hv;
    }
  }
}

// ---------------- fused Set2Set + memory LSTM; wave0 serial attention ----
__global__ __launch_bounds__(256) void s2s_kernel(
    const float* __restrict__ h,
    const float* __restrict__ wihT, const float* __restrict__ whhT,
    const float* __restrict__ mwihT, const float* __restrict__ fb,
    float* __restrict__ hx_f32, float* __restrict__ dout) {
  __shared__ float outL[64][65];
  __shared__ float qs[128];
  __shared__ float hsv[64], csv[64], sg[256], sa[64];
  const int t = threadIdx.x;
  const int g = blockIdx.x;
  float wr[128];
#pragma unroll
  for (int j = 0; j < 128; j++) wr[j] = wihT[j * 256 + t];
  for (int idx = t; idx < 64 * 64; idx += 256) outL[idx >> 6][idx & 63] = h[g * 4096 + idx];
  if (t < 128) qs[t] = 0.f;
  if (t < 64) { hsv[t] = 0.f; csv[t] = 0.f; }
  __syncthreads();
  for (int step = 0; step < 6; step++) {
    float acc = fb[1152 + t] + fb[1408 + t];
#pragma unroll
    for (int j = 0; j < 128; j++) acc += qs[j] * wr[j];
#pragma unroll 8
    for (int j = 0; j < 64; j++) acc += hsv[j] * whhT[j * 256 + t];
    sg[t] = acc;
    __syncthreads();
    if (t < 64) {
      float cn = sigm(sg[64 + t]) * csv[t] + sigm(sg[t]) * tanh_f(sg[128 + t]);
      csv[t] = cn;
      float hv = sigm(sg[192 + t]) * tanh_f(cn);
      hsv[t] = hv;
      float e = 0.f;
      for (int d2 = 0; d2 < 64; d2++) e += outL[t][d2] * hsv[d2];
      float mx = e;
      for (int off = 32; off > 0; off >>= 1) mx = fmaxf(mx, __shfl_xor(mx, off));
      float a = __expf(e - mx);
      float s = a;
      for (int off = 32; off > 0; off >>= 1) s += __shfl_xor(s, off);
      sa[t] = a / s;
      float r = 0.f;
      for (int n2 = 0; n2 < 64; n2++) r += sa[n2] * outL[n2][t];
      qs[t] = hv;
      qs[64 + t] = r;
    }
    __syncthreads();
  }
  float acc = fb[1664 + t] + fb[1920 + t];
#pragma unroll 8
  for (int j = 0; j < 128; j++) acc += qs[j] * mwihT[j * 256 + t];
  sg[t] = acc;
  __syncthreads();
  if (t < 64) {
    float cn = sigm(sg[t]) * tanh_f(sg[128 + t]);
    float hn = sigm(sg[192 + t]) * tanh_f(cn);
    hx_f32[g * 64 + t] = hn;
    dout[TTOT * 6 + g * 64 + t] = hn;
    dout[TTOT * 6 + NG * 64 + g * 64 + t] = cn;
  }
}

// ---------------- head: faithful permute/reshape + lin1 + lin2 ----
__global__ __launch_bounds__(64) void head_kernel(
    const float* __restrict__ h, const float* __restrict__ hx_f32,
    const int* __restrict__ nonring, const int* __restrict__ nrbidx,
    const float* __restrict__ l1wT, const float* __restrict__ l2w,
    const float* __restrict__ fb, float* __restrict__ dout) {
  __shared__ float feat[320];
  __shared__ float so1[64];
  const int r = blockIdx.x;
  const int lane = threadIdx.x;
  const int blk = r % 48, di = r / 48;
  const int tt = blk * 64 + lane;
  feat[lane * 5] = hx_f32[nrbidx[tt] * 64 + di];
#pragma unroll
  for (int s = 1; s <= 4; s++)
    feat[lane * 5 + s] = h[nonring[(s - 1) * TTOT + tt] * 64 + di];
  __syncthreads();
  float acc = fb[2176 + lane];
#pragma unroll 8
  for (int c = 0; c < 320; c++) acc += feat[c] * l1wT[c * 64 + lane];
  so1[lane] = fmaxf(acc, 0.f);
  __syncthreads();
  if (lane < 6) {
    float a2 = fb[2240 + lane];
    for (int j = 0; j < 64; j++) a2 += so1[j] * l2w[lane * 64 + j];
    dout[r * 6 + lane] = a2;
  }
}

extern "C" void kernel_launch(void* const* d_in, const int* in_sizes, int n_in,
                              void* d_out, int out_size, void* d_ws, size_t ws_size,
                              hipStream_t stream) {
  (void)in_sizes; (void)n_in; (void)out_size;
  const float* x         = (const float*)d_in[0];
  const float* edge_attr = (const float*)d_in[1];
  const int* edge_index  = (const int*)d_in[2];
  const int* nonring     = (const int*)d_in[4];
  const int* nrbidx      = (const int*)d_in[5];
  float* out = (float*)d_out;

  char* ws = (char*)d_ws;
  float*    h      = (float*)(ws + WS_H);
  float*    agg    = (float*)(ws + WS_AGG);
  _Float16* w2     = (_Float16*)(ws + WS_W2);
  _Float16* rtH    = (_Float16*)(ws + WS_RT);
  _Float16* whhH   = (_Float16*)(ws + WS_WHH);
  _Float16* wihH   = (_Float16*)(ws + WS_WIH);
  float*    swihT  = (float*)(ws + WS_SWIHT);
  float*    swhhT  = (float*)(ws + WS_SWHHT);
  float*    mwihT  = (float*)(ws + WS_MWIHT);
  float*    l1wT   = (float*)(ws + WS_L1WT);
  float*    l2wF   = (float*)(ws + WS_L2WF);
  float*    fb     = (float*)(ws + WS_FB);
  float*    deg    = (float*)(ws + WS_DEG);
  float*    hx_f32 = (float*)(ws + WS_HX);
  if (ws_size < (size_t)WS_NEED) return;

  Srcs S;
  S.p[0] = d_in[8];   S.p[1] = d_in[9];   S.p[2] = d_in[10];  S.p[3] = d_in[11];
  S.p[4] = d_in[12];  S.p[5] = d_in[13];  S.p[6] = d_in[14];  S.p[7] = d_in[15];
  S.p[8] = d_in[16];  S.p[9] = d_in[17];  S.p[10] = d_in[18]; S.p[11] = d_in[19];
  S.p[12] = d_in[20]; S.p[13] = d_in[21]; S.p[14] = d_in[22]; S.p[15] = d_in[23];
  S.p[16] = d_in[24]; S.p[17] = d_in[26]; S.p[18] = d_in[27]; S.p[19] = d_in[28];
  S.p[20] = d_in[29]; S.p[21] = d_in[30]; S.p[22] = d_in[31];

  setup1_kernel<<<(SETUP1_N + 255) / 256, 256, 0, stream>>>(S, ws);
  setup2_kernel<<<(SETUP2_N + 255) / 256, 256, 0, stream>>>(x, edge_index, ws);

  for (int it = 0; it < 6; it++) {
    msg_kernel<<<NEDGE / 64, 512, 0, stream>>>(h, edge_attr, fb, w2, edge_index, agg);
    update_kernel<<<NNODE / 16, 64, 0, stream>>>(h, agg, deg, rtH, whhH, wihH, fb);
  }

  s2s_kernel<<<NG, 256, 0, stream>>>(h, swihT, swhhT, mwihT, fb, hx_f32, out);
  head_kernel<<<TTOT, 64, 0, stream>>>(h, hx_f32, nonring, nrbidx, l1wT, l2wF, fb, out);
}

// Round 17
// 443.395 us; speedup vs baseline: 2.3561x; 2.3561x over previous
//
#include <hip/hip_runtime.h>

#define NNODE 16384
#define NEDGE 32768
#define NG    256
#define TPGx  12
#define TTOT  (NG * TPGx)   // 3072
#define D     64

typedef _Float16 h8 __attribute__((ext_vector_type(8)));
typedef _Float16 h4 __attribute__((ext_vector_type(4)));
typedef float    f4 __attribute__((ext_vector_type(4)));

static __device__ __forceinline__ float sigm(float x) { return 1.f / (1.f + __expf(-x)); }

static __device__ __forceinline__ f4 mfma16h(h8 a, h8 b, f4 c) {
  return __builtin_amdgcn_mfma_f32_16x16x32_f16(a, b, c, 0, 0, 0);
}

static __device__ __forceinline__ h8 splat16(_Float16 x) {
  h8 v = {x, x, x, x, x, x, x, x};
  return v;
}

// ---------------- workspace layout (byte offsets) ----------------
#define WS_H      0          // float [N*64]   4 MiB
#define WS_AGG    4194304    // float [N*64]   4 MiB
#define WS_W2     8388608    // fp16 [65 tiles * 4096]; tile i idx=((k>>3)*64+o)*8+(k&7)
#define WS_RT     8921088    // fp16 [64*64]  rt[o][i]
#define WS_WHH    8929280    // fp16 [192*64] natural [oo][i]
#define WS_WIH    8953856    // fp16 [192*64]
#define WS_SWIHT  8978432    // f32 [128][256] transposed
#define WS_SWHHT  9109504    // f32 [64][256]  transposed
#define WS_MWIHT  9175040    // f32 [128][256] transposed
#define WS_L1WT   9306112    // f32 [320][64]  transposed
#define WS_L2WF   9388032    // f32 [6*64]
#define WS_FB     9389568    // f32 [2246]
#define WS_DEG    9398784    // f32 [N]
#define WS_HX     9464320    // f32 [G*64]
#define WS_NEED   9529856
// fb sub-offsets (floats): lin0w 0, lin0b 192, e1w 256, e1b 640, convb 704,
// gbih 768, gbhh 960, s2sbih 1152, s2sbhh 1408, membih 1664, membhh 1920,
// l1b 2176, l2b 2240

// ---------------- pack fp32 params; GEMM weights -> fp16; s2s/head transposed ------
struct Srcs { const void* p[23]; };

__device__ __constant__ const int kCum[24] = {
    0, 192, 256, 640, 704, 262848, 266944, 271040, 271104, 283392, 295680,
    295872, 296064, 328832, 345216, 345472, 345728, 378496, 378752, 379008,
    399488, 399552, 399936, 399942};

__global__ __launch_bounds__(256) void pack_kernel(Srcs S, char* __restrict__ ws) {
  int idx = blockIdx.x * 256 + threadIdx.x;
  if (idx >= 399942) return;
  int r = 0, base = 0;
#pragma unroll
  for (int k = 0; k < 23; k++)
    if (idx >= kCum[k]) { r = k; base = kCum[k]; }
  int li = idx - base;
  float v = ((const float*)S.p[r])[li];

  float*    fb    = (float*)(ws + WS_FB);
  _Float16* w2    = (_Float16*)(ws + WS_W2);
  _Float16* rtH   = (_Float16*)(ws + WS_RT);
  _Float16* whhH  = (_Float16*)(ws + WS_WHH);
  _Float16* wihH  = (_Float16*)(ws + WS_WIH);
  float*    swihT = (float*)(ws + WS_SWIHT);
  float*    swhhT = (float*)(ws + WS_SWHHT);
  float*    mwihT = (float*)(ws + WS_MWIHT);
  float*    l1wT  = (float*)(ws + WS_L1WT);
  float*    l2w   = (float*)(ws + WS_L2WF);

  switch (r) {
    case 0: fb[li] = v; break;          // lin0_w
    case 1: fb[192 + li] = v; break;    // lin0_b
    case 2: fb[256 + li] = v; break;    // e1_w
    case 3: fb[640 + li] = v; break;    // e1_b
    case 4: {                           // e2_w flat (i*64+o)*64+k -> tile i
      int i = li >> 12, o = (li >> 6) & 63, k = li & 63;
      w2[i * 4096 + (((k >> 3) * 64 + o) << 3) + (k & 7)] = (_Float16)v;
    } break;
    case 5: {                           // e2_b flat k*64+o -> tile 64
      int k = li >> 6, o = li & 63;
      w2[64 * 4096 + (((k >> 3) * 64 + o) << 3) + (k & 7)] = (_Float16)v;
    } break;
    case 6: {                           // root_w [i][o] -> rt[o*64+i]
      int i = li >> 6, o = li & 63;
      rtH[o * 64 + i] = (_Float16)v;
    } break;
    case 7: fb[704 + li] = v; break;    // conv_b
    case 8: wihH[li] = (_Float16)v; break;   // gru_wih [oo][i]
    case 9: whhH[li] = (_Float16)v; break;   // gru_whh [oo][i]
    case 10: fb[768 + li] = v; break;   // gru_bih
    case 11: fb[960 + li] = v; break;   // gru_bhh
    case 12: swihT[(li & 127) * 256 + (li >> 7)] = v; break;  // s2s_wih [256][128]
    case 13: swhhT[(li & 63) * 256 + (li >> 6)] = v; break;   // s2s_whh [256][64]
    case 14: fb[1152 + li] = v; break;  // s2s_bih
    case 15: fb[1408 + li] = v; break;  // s2s_bhh
    case 16: mwihT[(li & 127) * 256 + (li >> 7)] = v; break;  // mem_wih [256][128]
    case 17: fb[1664 + li] = v; break;  // mem_bih
    case 18: fb[1920 + li] = v; break;  // mem_bhh
    case 19: l1wT[(li % 320) * 64 + (li / 320)] = v; break;   // lin1_w [64][320]
    case 20: fb[2176 + li] = v; break;  // lin1_b
    case 21: l2w[li] = v; break;
    case 22: fb[2240 + li] = v; break;  // lin2_b
  }
}

// ---------------- node init: h = relu(x @ lin0_w.T + lin0_b), fp32 ----------------
__global__ __launch_bounds__(256) void init_kernel(
    const float* __restrict__ x, const float* __restrict__ fb,
    float* __restrict__ h) {
  int idx = blockIdx.x * 256 + threadIdx.x;  // n*64+o
  int n = idx >> 6, o = idx & 63;
  float acc = fb[192 + o];
#pragma unroll
  for (int j = 0; j < 3; j++) acc += x[n * 3 + j] * fb[o * 3 + j];
  h[idx] = fmaxf(acc, 0.f);
}

// ---------------- degree ----------------
__global__ __launch_bounds__(256) void deg_kernel(const int* __restrict__ edge_index,
                                                  float* __restrict__ deg) {
  int e = blockIdx.x * 256 + threadIdx.x;
  if (e < NEDGE) atomicAdd(&deg[edge_index[NEDGE + e]], 1.0f);
}

// ---------------- message GEMM, fp16; register-streamed B (no LDS staging) --------
// 256 threads = 4 waves; 64 edges/block; wave = 64 edges x 16 cols (nt = wave).
__global__ __launch_bounds__(256) void msg_kernel(
    const float* __restrict__ h, const float* __restrict__ ea,
    const float* __restrict__ fb, const _Float16* __restrict__ w2,
    const int* __restrict__ edge_index, float* __restrict__ agg) {
  __shared__ _Float16 sOut[64][72];    // 9 KB
  const int tid = threadIdx.x;
  const int wave = tid >> 6, lane = tid & 63;
  const int m15 = lane & 15, quad = lane >> 4;
  const int eb = blockIdx.x * 64;
  {  // stage out[src] as fp16 for 64 edges
    int r = tid >> 2, c0 = (tid & 3) * 16;
    int srcn = edge_index[eb + r];
#pragma unroll
    for (int c = c0; c < c0 + 16; c += 4) {
      float4 v = *(const float4*)&h[srcn * D + c];
      sOut[r][c]     = (_Float16)v.x;
      sOut[r][c + 1] = (_Float16)v.y;
      sOut[r][c + 2] = (_Float16)v.z;
      sOut[r][c + 3] = (_Float16)v.w;
    }
  }
  // edge hidden (fp32 compute, fp16 store) for 4 edges/lane: e = eb + r*16 + m15
  h8 hid0[4], hid1[4];
#pragma unroll
  for (int r = 0; r < 4; r++) {
    int e = eb + r * 16 + m15;
    float eav[6];
#pragma unroll
    for (int j = 0; j < 6; j++) eav[j] = ea[e * 6 + j];
#pragma unroll
    for (int j = 0; j < 8; j++) {
      int k0 = quad * 8 + j, k1 = 32 + quad * 8 + j;
      float a0 = fb[640 + k0], a1 = fb[640 + k1];
#pragma unroll
      for (int jj = 0; jj < 6; jj++) {
        a0 += eav[jj] * fb[256 + k0 * 6 + jj];
        a1 += eav[jj] * fb[256 + k1 * 6 + jj];
      }
      hid0[r][j] = (_Float16)fmaxf(a0, 0.f);
      hid1[r][j] = (_Float16)fmaxf(a1, 0.f);
    }
  }
  __syncthreads();
  // per-lane B fragment pointers (L2-resident, coalesced dwordx4 per lane)
  const _Float16* bp0 = w2 + (quad * 64 + wave * 16 + m15) * 8;        // kc = quad
  const _Float16* bp1 = w2 + ((4 + quad) * 64 + wave * 16 + m15) * 8;  // kc = 4+quad
  f4 zz = {0.f, 0.f, 0.f, 0.f};
  f4 acc[4];
#pragma unroll
  for (int r = 0; r < 4; r++) acc[r] = zz;
  h8 c0[4], c1[4];
#pragma unroll
  for (int t = 0; t < 4; t++) {
    c0[t] = *(const h8*)(bp0 + t * 4096);
    c1[t] = *(const h8*)(bp1 + t * 4096);
  }
#pragma unroll
  for (int p = 0; p < 16; p++) {
    h8 n0[4], n1[4];
    if (p < 15) {
#pragma unroll
      for (int t = 0; t < 4; t++) {
        int i = (p + 1) * 4 + t;
        n0[t] = *(const h8*)(bp0 + i * 4096);
        n1[t] = *(const h8*)(bp1 + i * 4096);
      }
    }
#pragma unroll
    for (int r = 0; r < 4; r++) {
      h4 os4 = *(const h4*)&sOut[r * 16 + m15][p * 4];
#pragma unroll
      for (int t = 0; t < 4; t++) {
        h8 os = splat16(os4[t]);
        acc[r] = mfma16h(hid0[r] * os, c0[t], acc[r]);
        acc[r] = mfma16h(hid1[r] * os, c1[t], acc[r]);
      }
    }
    if (p < 15) {
#pragma unroll
      for (int t = 0; t < 4; t++) { c0[t] = n0[t]; c1[t] = n1[t]; }
    }
  }
  {  // bias tail (tile 64): z = out_src
    h8 b0 = *(const h8*)(bp0 + 64 * 4096);
    h8 b1 = *(const h8*)(bp1 + 64 * 4096);
#pragma unroll
    for (int r = 0; r < 4; r++) {
      h8 a0 = *(const h8*)&sOut[r * 16 + m15][quad * 8];
      h8 a1 = *(const h8*)&sOut[r * 16 + m15][32 + quad * 8];
      acc[r] = mfma16h(a0, b0, acc[r]);
      acc[r] = mfma16h(a1, b1, acc[r]);
    }
  }
#pragma unroll
  for (int r = 0; r < 4; r++) {
#pragma unroll
    for (int reg = 0; reg < 4; reg++) {
      int ee = eb + r * 16 + quad * 4 + reg;
      int dn = edge_index[NEDGE + ee];
      atomicAdd(agg + dn * D + wave * 16 + m15, acc[r][reg]);
    }
  }
}

// ---------------- node update, fp16 MFMA; zeroes agg for the next iteration ----
__global__ __launch_bounds__(256) void update_kernel(
    float* __restrict__ h, float* __restrict__ agg, const float* __restrict__ deg,
    const _Float16* __restrict__ rtH, const _Float16* __restrict__ whhH,
    const _Float16* __restrict__ wihH, const float* __restrict__ fb) {
  __shared__ float buf[64][68];  // sH, then (after barrier) sM
  const int tid = threadIdx.x;
  const int wave = tid >> 6, lane = tid & 63;
  const int m15 = lane & 15, quad = lane >> 4;
  const int nb = blockIdx.x * 64;
  {
    int r = tid >> 2, c0 = (tid & 3) * 16;
#pragma unroll
    for (int c = c0; c < c0 + 16; c += 4)
      *(float4*)&buf[r][c] = *(const float4*)&h[(nb + r) * D + c];
  }
  __syncthreads();
  const int mrow = wave * 16 + m15;
  h8 a0, a1;
#pragma unroll
  for (int j = 0; j < 8; j++) {
    a0[j] = (_Float16)buf[mrow][quad * 8 + j];
    a1[j] = (_Float16)buf[mrow][32 + quad * 8 + j];
  }
  f4 zz = {0.f, 0.f, 0.f, 0.f};
  f4 acc[16];
#pragma unroll
  for (int nt = 0; nt < 16; nt++) acc[nt] = zz;
#pragma unroll
  for (int nt = 0; nt < 16; nt++) {
    int nn = nt * 16 + m15;
    const _Float16* bp = (nt < 4) ? (rtH + nn * D) : (whhH + (nn - 64) * D);
    h8 bh0 = *(const h8*)(bp + quad * 8);
    h8 bh1 = *(const h8*)(bp + 32 + quad * 8);
    f4 a = acc[nt];
    a = mfma16h(a0, bh0, a);
    a = mfma16h(a1, bh1, a);
    acc[nt] = a;
  }
  __syncthreads();  // everyone done reading sH
  // m = relu(root + agg/deg + conv_b), fp32, into buf; zero agg behind us
#pragma unroll
  for (int nt = 0; nt < 4; nt++) {
#pragma unroll
    for (int reg = 0; reg < 4; reg++) {
      int nloc = wave * 16 + quad * 4 + reg;
      int o = nt * 16 + m15;
      float dg = fmaxf(deg[nb + nloc], 1.f);
      int aidx = (nb + nloc) * D + o;
      float v = acc[nt][reg] + agg[aidx] / dg + fb[704 + o];
      agg[aidx] = 0.f;
      buf[nloc][o] = fmaxf(v, 0.f);
    }
  }
  __syncthreads();
  h8 m0, m1;
#pragma unroll
  for (int j = 0; j < 8; j++) {
    m0[j] = (_Float16)buf[mrow][quad * 8 + j];
    m1[j] = (_Float16)buf[mrow][32 + quad * 8 + j];
  }
  f4 g2[12];
#pragma unroll
  for (int nt = 0; nt < 12; nt++) g2[nt] = zz;
#pragma unroll
  for (int nt = 0; nt < 12; nt++) {
    int nn = nt * 16 + m15;
    const _Float16* bp = wihH + nn * D;
    h8 bh0 = *(const h8*)(bp + quad * 8);
    h8 bh1 = *(const h8*)(bp + 32 + quad * 8);
    f4 a = g2[nt];
    a = mfma16h(m0, bh0, a);
    a = mfma16h(m1, bh1, a);
    g2[nt] = a;
  }
#pragma unroll
  for (int nt = 0; nt < 4; nt++) {
#pragma unroll
    for (int reg = 0; reg < 4; reg++) {
      int nloc = wave * 16 + quad * 4 + reg;
      int o = nt * 16 + m15;
      int gidx = (nb + nloc) * D + o;
      float gir = g2[nt][reg]      + fb[768 + o];
      float giz = g2[nt + 4][reg]  + fb[768 + 64 + o];
      float gin = g2[nt + 8][reg]  + fb[768 + 128 + o];
      float ghr = acc[nt + 4][reg]  + fb[960 + o];
      float ghz = acc[nt + 8][reg]  + fb[960 + 64 + o];
      float ghn = acc[nt + 12][reg] + fb[960 + 128 + o];
      float rr = sigm(gir + ghr);
      float zg = sigm(giz + ghz);
      float nnv = tanhf(gin + rr * ghn);
      float hv = h[gidx];
      h[gidx] = (1.f - zg) * nnv + zg * hv;
    }
  }
}

// ---------------- fused Set2Set (6 steps) + memory LSTM; wih in registers ----
__global__ __launch_bounds__(256) void s2s_kernel(
    const float* __restrict__ h,
    const float* __restrict__ wihT, const float* __restrict__ whhT,
    const float* __restrict__ mwihT, const float* __restrict__ fb,
    float* __restrict__ hx_f32, float* __restrict__ dout) {
  __shared__ float outL[64][65];
  __shared__ float qs[128];
  __shared__ float hsv[64], csv[64], sg[256], sa[64];
  __shared__ float spart[4][64];
  const int t = threadIdx.x;
  const int g = blockIdx.x;
  float wr[128];
#pragma unroll
  for (int j = 0; j < 128; j++) wr[j] = wihT[j * 256 + t];
  for (int idx = t; idx < 64 * 64; idx += 256) outL[idx >> 6][idx & 63] = h[g * 4096 + idx];
  if (t < 128) qs[t] = 0.f;
  if (t < 64) { hsv[t] = 0.f; csv[t] = 0.f; }
  __syncthreads();
  for (int step = 0; step < 6; step++) {
    float acc = fb[1152 + t] + fb[1408 + t];
#pragma unroll
    for (int j = 0; j < 128; j++) acc += qs[j] * wr[j];
#pragma unroll 8
    for (int j = 0; j < 64; j++) acc += hsv[j] * whhT[j * 256 + t];
    sg[t] = acc;
    __syncthreads();
    if (t < 64) {
      float cn = sigm(sg[64 + t]) * csv[t] + sigm(sg[t]) * tanhf(sg[128 + t]);
      csv[t] = cn;
      hsv[t] = sigm(sg[192 + t]) * tanhf(cn);
    }
    __syncthreads();
    if (t < 64) {
      float e = 0.f;
      for (int d2 = 0; d2 < 64; d2++) e += outL[t][d2] * hsv[d2];
      float mx = e;
      for (int off = 32; off > 0; off >>= 1) mx = fmaxf(mx, __shfl_xor(mx, off));
      float a = __expf(e - mx);
      float s = a;
      for (int off = 32; off > 0; off >>= 1) s += __shfl_xor(s, off);
      sa[t] = a / s;
    }
    __syncthreads();
    {
      int o = t & 63, part = t >> 6;
      float r = 0.f;
      for (int n2 = part * 16; n2 < part * 16 + 16; n2++) r += sa[n2] * outL[n2][o];
      spart[part][o] = r;
    }
    __syncthreads();
    if (t < 64) {
      qs[t] = hsv[t];
      qs[64 + t] = spart[0][t] + spart[1][t] + spart[2][t] + spart[3][t];
    }
    __syncthreads();
  }
  float acc = fb[1664 + t] + fb[1920 + t];
#pragma unroll 8
  for (int j = 0; j < 128; j++) acc += qs[j] * mwihT[j * 256 + t];
  sg[t] = acc;
  __syncthreads();
  if (t < 64) {
    float cn = sigm(sg[t]) * tanhf(sg[128 + t]);
    float hn = sigm(sg[192 + t]) * tanhf(cn);
    hx_f32[g * 64 + t] = hn;
    dout[TTOT * 6 + g * 64 + t] = hn;
    dout[TTOT * 6 + NG * 64 + g * 64 + t] = cn;
  }
}

// ---------------- head: faithful permute/reshape + lin1 + lin2; transposed l1w ----
__global__ __launch_bounds__(64) void head_kernel(
    const float* __restrict__ h, const float* __restrict__ hx_f32,
    const int* __restrict__ nonring, const int* __restrict__ nrbidx,
    const float* __restrict__ l1wT, const float* __restrict__ l2w,
    const float* __restrict__ fb, float* __restrict__ dout) {
  __shared__ float feat[320];
  __shared__ float so1[64];
  const int r = blockIdx.x;
  const int lane = threadIdx.x;
  const int blk = r % 48, di = r / 48;
  const int tt = blk * 64 + lane;
  feat[lane * 5] = hx_f32[nrbidx[tt] * 64 + di];
#pragma unroll
  for (int s = 1; s <= 4; s++)
    feat[lane * 5 + s] = h[nonring[(s - 1) * TTOT + tt] * 64 + di];
  __syncthreads();
  float acc = fb[2176 + lane];
#pragma unroll 8
  for (int c = 0; c < 320; c++) acc += feat[c] * l1wT[c * 64 + lane];
  so1[lane] = fmaxf(acc, 0.f);
  __syncthreads();
  if (lane < 6) {
    float a2 = fb[2240 + lane];
    for (int j = 0; j < 64; j++) a2 += so1[j] * l2w[lane * 64 + j];
    dout[r * 6 + lane] = a2;
  }
}

extern "C" void kernel_launch(void* const* d_in, const int* in_sizes, int n_in,
                              void* d_out, int out_size, void* d_ws, size_t ws_size,
                              hipStream_t stream) {
  (void)in_sizes; (void)n_in; (void)out_size;
  const float* x         = (const float*)d_in[0];
  const float* edge_attr = (const float*)d_in[1];
  const int* edge_index  = (const int*)d_in[2];
  const int* nonring     = (const int*)d_in[4];
  const int* nrbidx      = (const int*)d_in[5];
  float* out = (float*)d_out;

  char* ws = (char*)d_ws;
  float*    h      = (float*)(ws + WS_H);
  float*    agg    = (float*)(ws + WS_AGG);
  _Float16* w2     = (_Float16*)(ws + WS_W2);
  _Float16* rtH    = (_Float16*)(ws + WS_RT);
  _Float16* whhH   = (_Float16*)(ws + WS_WHH);
  _Float16* wihH   = (_Float16*)(ws + WS_WIH);
  float*    swihT  = (float*)(ws + WS_SWIHT);
  float*    swhhT  = (float*)(ws + WS_SWHHT);
  float*    mwihT  = (float*)(ws + WS_MWIHT);
  float*    l1wT   = (float*)(ws + WS_L1WT);
  float*    l2wF   = (float*)(ws + WS_L2WF);
  float*    fb     = (float*)(ws + WS_FB);
  float*    deg    = (float*)(ws + WS_DEG);
  float*    hx_f32 = (float*)(ws + WS_HX);
  if (ws_size < (size_t)WS_NEED) return;

  Srcs S;
  S.p[0] = d_in[8];   S.p[1] = d_in[9];   S.p[2] = d_in[10];  S.p[3] = d_in[11];
  S.p[4] = d_in[12];  S.p[5] = d_in[13];  S.p[6] = d_in[14];  S.p[7] = d_in[15];
  S.p[8] = d_in[16];  S.p[9] = d_in[17];  S.p[10] = d_in[18]; S.p[11] = d_in[19];
  S.p[12] = d_in[20]; S.p[13] = d_in[21]; S.p[14] = d_in[22]; S.p[15] = d_in[23];
  S.p[16] = d_in[24]; S.p[17] = d_in[26]; S.p[18] = d_in[27]; S.p[19] = d_in[28];
  S.p[20] = d_in[29]; S.p[21] = d_in[30]; S.p[22] = d_in[31];
  pack_kernel<<<(399942 + 255) / 256, 256, 0, stream>>>(S, ws);

  init_kernel<<<NNODE * D / 256, 256, 0, stream>>>(x, fb, h);
  hipMemsetAsync(deg, 0, NNODE * 4, stream);
  hipMemsetAsync(agg, 0, NNODE * D * 4, stream);
  deg_kernel<<<NEDGE / 256, 256, 0, stream>>>(edge_index, deg);

  for (int it = 0; it < 6; it++) {
    msg_kernel<<<NEDGE / 64, 256, 0, stream>>>(h, edge_attr, fb, w2, edge_index, agg);
    update_kernel<<<NNODE / 64, 256, 0, stream>>>(h, agg, deg, rtH, whhH, wihH, fb);
  }

  s2s_kernel<<<NG, 256, 0, stream>>>(h, swihT, swhhT, mwihT, fb, hx_f32, out);
  head_kernel<<<TTOT, 64, 0, stream>>>(h, hx_f32, nonring, nrbidx, l1wT, l2wF, fb, out);
}